// Round 10
// baseline (11714.844 us; speedup 1.0000x reference)
//
#include <hip/hip_runtime.h>

#define T_STEPS 1024
#define N_IN    128
#define H       256
#define N_OUT   64
#define WARM    10

#define XL32(X) X(0)X(1)X(2)X(3)X(4)X(5)X(6)X(7)X(8)X(9)X(10)X(11)X(12)X(13)X(14)X(15) \
                X(16)X(17)X(18)X(19)X(20)X(21)X(22)X(23)X(24)X(25)X(26)X(27)X(28)X(29)X(30)X(31)

// Bit-exact ascending sparse walk over a segmented compact index list.
// seg[w*64 + r] holds the r-th spiking neuron index within word w (ascending),
// padded to the batch width with index 256 -> a zero row appended to the
// transposed weight matrices (adds +0.0f, an exact identity). Single
// accumulator, strict ascending adds == numpy's dense k-sequential chain.
// All 32 loads per batch are independent (no serial mask chain), so they
// issue together and L2 latency is paid once per batch, not per element.
template<bool SEL>
__device__ __forceinline__ float walkSeg(const int* __restrict__ seg,
                                         const int* __restrict__ cnt,
                                         const float* __restrict__ colp,
                                         int sjj) {
  float a = 0.f;
#pragma unroll
  for (int w = 0; w < 4; ++w) {
    const int n = cnt[w];                 // LDS broadcast, block-uniform
    const int* sp = seg + (w << 6);
    for (int q = 0; q < n; q += 32) {     // n <= 64 -> q in {0,32}; sp[q+31] <= sp[63] in-bounds
#define GR(k) float v##k; { int j = sp[q + k];                                   \
                            float tv = colp[(size_t)j * (size_t)sjj];            \
                            v##k = (!SEL || (q + k < n)) ? tv : 0.0f; }
      XL32(GR)
#undef GR
#define AD(k) a += v##k;
      XL32(AD)
#undef AD
    }
  }
  return a;
}

// ---------- prep: transpose weights into ws, each with a 257th ZERO row ----------
// ws floats: Wh1T @0 (257*256) | W12T @65792 | Wh2T @131584 | WoutT @197376 (257*64)
// WT[j][i] = W[i][j] for j<256; row j==256 is all zeros (pad target).
__global__ void srnn_prep(const float* __restrict__ Wh1,
                          const float* __restrict__ W12,
                          const float* __restrict__ Wh2,
                          const float* __restrict__ Wout,
                          float* __restrict__ ws) {
  int idx = blockIdx.x * 256 + (int)threadIdx.x;     // 0 .. 213823
  if (idx >= 3 * 65792 + 16448) return;
  if (idx < 3 * 65792) {
    int mat = idx / 65792;
    int rem = idx - mat * 65792;
    int j = rem >> 8, i = rem & 255;
    const float* src = (mat == 0) ? Wh1 : (mat == 1) ? W12 : Wh2;
    ws[idx] = (j < H) ? src[i * H + j] : 0.0f;
  } else {
    int rem = idx - 3 * 65792;
    int j = rem >> 6, o = rem & 63;
    ws[idx] = (j < H) ? Wout[o * H + j] : 0.0f;
  }
}

// ---------- faithful-f32-order scan: 1 block (1024 thr) per batch row ----------
// G0: x-dot + both membrane updates; G1: h1-walk; G2: h2-walk; G3: readout + x-prefetch.
template<int MODE>   // 0: transposed ws layout (zero-row pads); 1: original layout (selects)
__launch_bounds__(1024)
__global__ void srnn_scan(const float* __restrict__ x,
                          const float* __restrict__ Win,
                          const float* __restrict__ bin_p, const float* __restrict__ bh1_p,
                          const float* __restrict__ b12_p, const float* __restrict__ bh2_p,
                          const float* __restrict__ Wh1b, int h1i, int h1j,
                          const float* __restrict__ W12b, int c12i, int c12j,
                          const float* __restrict__ Wh2b, int h2i, int h2j,
                          const float* __restrict__ Wob,  int woi, int woj,
                          const float* __restrict__ bo_p,
                          float* __restrict__ out) {
  __shared__ float win_lds[N_IN * 257];            // [k][i] padded stride -> bank-conflict-free
  __shared__ float xs[2][N_IN];
  __shared__ float xw[H], h1d[H], h2d[H], c12[H];
  __shared__ int   idx1[H], idx2[H];               // segmented compact spike lists
  __shared__ int   cnt1[4], cnt2[4];

  const int tid = (int)threadIdx.x;
  const int g   = tid >> 8;        // group 0..3
  const int i   = tid & 255;
  const int b   = (int)blockIdx.x;

  constexpr bool SEL  = (MODE == 1);
  const int      PADJ = (MODE == 0) ? H : 0;       // pad index -> zero row (or select-killed)

  // Stage W_in transposed into LDS: win_lds[k*257 + i] = W_in[i*128 + k].
  // Global reads coalesced; LDS writes stride 257 -> conflict-free.
  for (int q = tid; q < H * N_IN; q += 1024) {
    int i2 = q >> 7, k = q & (N_IN - 1);
    win_lds[k * 257 + i2] = Win[q];
  }

  const float bin_i = (tid < H) ? bin_p[i] : 0.f;
  const float bh1_i = (tid < H) ? bh1_p[i] : 0.f;
  const float b12_i = (tid < H) ? b12_p[i] : 0.f;
  const float bh2_i = (tid < H) ? bh2_p[i] : 0.f;
  const float bo_o  = (g == 3 && i < N_OUT) ? bo_p[i] : 0.f;

  if (tid < 4) cnt1[tid] = 0;
  else if (tid < 8) cnt2[tid - 4] = 0;
  if (tid < N_IN) xs[0][tid] = x[(size_t)b * (T_STEPS * N_IN) + tid];

  const float* h1c  = Wh1b + (size_t)i * h1i;
  const float* h2c  = Wh2b + (size_t)i * h2i;
  const float* c12c = W12b + (size_t)i * c12i;
  const float* woc  = Wob  + (size_t)(i & 63) * woi;

  float m1 = 0.f, m2 = 0.f, acc = 0.f;

  __syncthreads();

  for (int t = 0; t < T_STEPS; ++t) {
    const int cur = t & 1;

    // ---- Phase 1: x-dot | h1-walk | h2-walk | readout(t-1) + x-prefetch
    if (g == 0) {
      // Sequential k=0..127, single accumulator, FMA — numpy per-element order.
      float a = 0.f;
#pragma unroll 16
      for (int k = 0; k < N_IN; ++k)
        a = fmaf(xs[cur][k], win_lds[k * 257 + i], a);
      xw[i] = a;
    } else if (g == 1) {
      h1d[i] = walkSeg<SEL>(idx1, cnt1, h1c, h1j);
    } else if (g == 2) {
      h2d[i] = walkSeg<SEL>(idx2, cnt2, h2c, h2j);
    } else {
      if (i < N_OUT) {
        if (t > WARM) {                  // readout of s2(t-1), t-1 >= WARM
          float d = walkSeg<SEL>(idx2, cnt2, woc, woj);
          acc = acc + (d + bo_o);        // np order: (dot + b_out), then acc+
        }
      } else if (i >= 128 && t + 1 < T_STEPS) {
        int k = i - 128;
        xs[cur ^ 1][k] = x[(size_t)b * (T_STEPS * N_IN) + (size_t)(t + 1) * N_IN + k];
      }
    }
    __syncthreads();

    // ---- Phase 2: layer-1 membrane + spike + compact-list build (G0)
    if (tid < H) {
      float u1 = 0.9f * m1;
      u1 = u1 + xw[i];
      u1 = u1 + bin_i;
      u1 = u1 + h1d[i];
      u1 = u1 + bh1_i;
      bool sp = (u1 - 1.0f) > 0.0f;
      m1 = u1 - (sp ? 1.0f : 0.0f);
      unsigned long long bm = __ballot(sp);
      const int l = tid & 63, w = tid >> 6;
      idx1[tid] = PADJ;                                 // pad fill (wave-ordered before rank write)
      int rank = (int)__popcll(bm & ((1ull << l) - 1ull));
      if (sp) idx1[(w << 6) + rank] = tid;              // ascending within word, words ascending
      if (l == 0) cnt1[w] = (int)__popcll(bm);
    }
    __syncthreads();

    // ---- Phase 3: W_12 walk with SAME-step s1
    if (tid < H) c12[i] = walkSeg<SEL>(idx1, cnt1, c12c, c12j);
    __syncthreads();

    // ---- Phase 4: layer-2 membrane + spike + compact-list build (G0)
    if (tid < H) {
      float u2 = 0.9f * m2;
      u2 = u2 + c12[i];
      u2 = u2 + b12_i;
      u2 = u2 + h2d[i];
      u2 = u2 + bh2_i;
      bool sp = (u2 - 1.0f) > 0.0f;
      m2 = u2 - (sp ? 1.0f : 0.0f);
      unsigned long long bm = __ballot(sp);
      const int l = tid & 63, w = tid >> 6;
      idx2[tid] = PADJ;
      int rank = (int)__popcll(bm & ((1ull << l) - 1ull));
      if (sp) idx2[(w << 6) + rank] = tid;
      if (l == 0) cnt2[w] = (int)__popcll(bm);
    }
    __syncthreads();
  }

  // ---- final readout for t = 1023
  if (g == 3 && i < N_OUT) {
    float d = walkSeg<SEL>(idx2, cnt2, woc, woj);
    acc = acc + (d + bo_o);
    out[(size_t)b * N_OUT + i] = acc / 1014.0f;
  }
}

// ---------- launch ----------
extern "C" void kernel_launch(void* const* d_in, const int* in_sizes, int n_in,
                              void* d_out, int out_size, void* d_ws, size_t ws_size,
                              hipStream_t stream) {
  const float* x     = (const float*)d_in[0];
  const float* W_in  = (const float*)d_in[1];
  const float* b_in  = (const float*)d_in[2];
  const float* W_h1  = (const float*)d_in[3];
  const float* b_h1  = (const float*)d_in[4];
  const float* W_12  = (const float*)d_in[5];
  const float* b_12  = (const float*)d_in[6];
  const float* W_h2  = (const float*)d_in[7];
  const float* b_h2  = (const float*)d_in[8];
  const float* W_out = (const float*)d_in[9];
  const float* b_out = (const float*)d_in[10];
  float* out = (float*)d_out;
  float* wsf = (float*)d_ws;

  const int TOTAL = 3 * 65792 + 16448;               // 213,824 floats (with zero rows)
  const bool use_t = (ws_size >= (size_t)TOTAL * sizeof(float));

  if (use_t) {
    srnn_prep<<<(TOTAL + 255) / 256, 256, 0, stream>>>(W_h1, W_12, W_h2, W_out, wsf);
    srnn_scan<0><<<256, 1024, 0, stream>>>(
        x, W_in, b_in, b_h1, b_12, b_h2,
        wsf,          1, H,          // Wh1T: col i stride 1, row j stride 256
        wsf + 65792,  1, H,          // W12T
        wsf + 131584, 1, H,          // Wh2T
        wsf + 197376, 1, N_OUT,      // WoutT: col o stride 1, row j stride 64
        b_out, out);
  } else {
    srnn_scan<1><<<256, 1024, 0, stream>>>(
        x, W_in, b_in, b_h1, b_12, b_h2,
        W_h1,  H, 1,                 // original: row i stride 256, j stride 1
        W_12,  H, 1,
        W_h2,  H, 1,
        W_out, H, 1,
        b_out, out);
  }
}

// Round 11
// 6626.932 us; speedup vs baseline: 1.7678x; 1.7678x over previous
//
#include <hip/hip_runtime.h>

#define T_STEPS 1024
#define N_IN    128
#define H       256
#define N_OUT   64
#define WARM    10

// R7-validated bit-exact sparse walk: single accumulator, strict ascending j
// (== numpy's dense k-sequential chain; skipped terms contribute exactly +0.0f).
// 16 independent loads per batch issue together; serial ffs chain per batch.
__device__ __forceinline__ float walk16(const unsigned long long* __restrict__ m4,
                                        const float* __restrict__ base,
                                        int sjj, int sii, int i) {
  float a = 0.f;
#pragma unroll
  for (int w = 0; w < 4; ++w) {
    unsigned long long m = m4[w];
    const float* bp = base + (size_t)(w * 64) * sjj + (size_t)i * sii;
    while (m) {
      float t0,t1,t2,t3,t4,t5,t6,t7,t8,t9,t10,t11,t12,t13,t14,t15;
#define GRAB(tk) { int j = m ? (__ffsll(m) - 1) : 0;            \
                   float v = bp[(size_t)j * sjj];               \
                   tk = m ? v : 0.0f;                           \
                   m &= m - 1; }
      GRAB(t0)  GRAB(t1)  GRAB(t2)  GRAB(t3)
      GRAB(t4)  GRAB(t5)  GRAB(t6)  GRAB(t7)
      GRAB(t8)  GRAB(t9)  GRAB(t10) GRAB(t11)
      GRAB(t12) GRAB(t13) GRAB(t14) GRAB(t15)
#undef GRAB
      a += t0;  a += t1;  a += t2;  a += t3;
      a += t4;  a += t5;  a += t6;  a += t7;
      a += t8;  a += t9;  a += t10; a += t11;
      a += t12; a += t13; a += t14; a += t15;
    }
  }
  return a;
}

// ---------- pre 1 (R8-validated): xw[b][t][i] = sum_k x[b,t,k]*W_in[i,k] ----------
__launch_bounds__(256)
__global__ void srnn_xw(const float* __restrict__ x,
                        const float* __restrict__ Win,
                        float* __restrict__ xw) {
  __shared__ float win[N_IN * H];
  __shared__ float xt[32][N_IN];
  const int tid = (int)threadIdx.x;
  const int b  = (int)blockIdx.x >> 5;
  const int t0 = ((int)blockIdx.x & 31) * 32;
  for (int q = tid; q < H * N_IN; q += 256) {
    int i2 = q >> 7, k = q & (N_IN - 1);
    win[k * H + i2] = Win[q];
  }
  for (int q = tid; q < 32 * N_IN; q += 256) {
    int r = q >> 7, k = q & (N_IN - 1);
    xt[r][k] = x[((size_t)b * T_STEPS + t0 + r) * N_IN + k];
  }
  __syncthreads();
  const int i = tid;
  for (int r = 0; r < 32; r += 4) {
    float a0 = 0.f, a1 = 0.f, a2 = 0.f, a3 = 0.f;
#pragma unroll 16
    for (int k = 0; k < N_IN; ++k) {
      float wv = win[k * H + i];
      a0 = fmaf(xt[r + 0][k], wv, a0);
      a1 = fmaf(xt[r + 1][k], wv, a1);
      a2 = fmaf(xt[r + 2][k], wv, a2);
      a3 = fmaf(xt[r + 3][k], wv, a3);
    }
    xw[((size_t)b * T_STEPS + t0 + r + 0) * H + i] = a0;
    xw[((size_t)b * T_STEPS + t0 + r + 1) * H + i] = a1;
    xw[((size_t)b * T_STEPS + t0 + r + 2) * H + i] = a2;
    xw[((size_t)b * T_STEPS + t0 + r + 3) * H + i] = a3;
  }
}

// ---------- pre 2 (R7-validated): transpose Wh1/W12/Wh2 (HxH) + Wout ----------
__global__ void srnn_prep(const float* __restrict__ Wh1,
                          const float* __restrict__ W12,
                          const float* __restrict__ Wh2,
                          const float* __restrict__ Wout,
                          float* __restrict__ ws) {
  int idx = blockIdx.x * 256 + (int)threadIdx.x;     // 0 .. 212991
  if (idx < 3 * H * H) {
    int mat = idx >> 16;
    int rem = idx & (H * H - 1);
    int j = rem >> 8;
    int i = rem & (H - 1);
    const float* src = (mat == 0) ? Wh1 : (mat == 1) ? W12 : Wh2;
    ws[idx] = src[i * H + j];          // WT[j][i]
  } else {
    int rem = idx - 3 * H * H;
    int j = rem >> 6;
    int o = rem & (N_OUT - 1);
    ws[idx] = Wout[o * H + j];         // WoutT[j][o]
  }
}

// ---------- pipelined scan: ONE walk-latency per step ----------
// L(t):  G0: w12(t)->reg | G1: h2(t) | G2: h1(t+1) | G3: readout(t-1) [+x stage]
// M(t):  u2(t) (ballot s2) then u1(t+1) (ballot s1), both on tid<256.
template<int MODE>   // 0: xw precomputed; 1: in-scan x-dot via win_lds
__launch_bounds__(1024)
__global__ void srnn_scan3(const float* __restrict__ x,
                           const float* __restrict__ xw,
                           const float* __restrict__ Win,
                           const float* __restrict__ bin_p, const float* __restrict__ bh1_p,
                           const float* __restrict__ b12_p, const float* __restrict__ bh2_p,
                           const float* __restrict__ Wh1b, int h1j, int h1i,
                           const float* __restrict__ W12b, int c12j, int c12i,
                           const float* __restrict__ Wh2b, int h2j, int h2i,
                           const float* __restrict__ Wob,  int woj, int woi,
                           const float* __restrict__ bo_p,
                           float* __restrict__ out) {
  __shared__ float h1d[H], h2d[H];
  __shared__ unsigned long long s1m[2][4], s2m[2][4];
  __shared__ float win_lds[(MODE == 1) ? (N_IN * 257) : 1];   // stride-257: conflict-free
  __shared__ float xs[(MODE == 1) ? 2 : 1][N_IN];

  const int tid = (int)threadIdx.x;
  const int g   = tid >> 8;
  const int i   = tid & 255;
  const int b   = (int)blockIdx.x;

  if (MODE == 1) {
    for (int q = tid; q < H * N_IN; q += 1024) {
      int i2 = q >> 7, k = q & (N_IN - 1);
      win_lds[k * 257 + i2] = Win[q];
    }
    if (tid < N_IN) xs[0][tid] = x[(size_t)b * (T_STEPS * N_IN) + tid];
  }
  if (tid < 4)       { s1m[0][tid] = 0ull; s2m[0][tid] = 0ull; }
  else if (tid < 8)  { s1m[1][tid - 4] = 0ull; s2m[1][tid - 4] = 0ull; }

  const float bin_i = (tid < H) ? bin_p[i] : 0.f;
  const float bh1_i = (tid < H) ? bh1_p[i] : 0.f;
  const float b12_i = (tid < H) ? b12_p[i] : 0.f;
  const float bh2_i = (tid < H) ? bh2_p[i] : 0.f;
  const float bo_o  = (g == 3 && i < N_OUT) ? bo_p[i] : 0.f;

  float m1 = 0.f, m2 = 0.f, acc = 0.f, c12v = 0.f, xv_next = 0.f;

  __syncthreads();   // staging + mask zero visible

  // ---- prologue "M(-1)": u1(0) = ((((0.9*0)+xdot)+b_in)+0.0)+b_h1; ballot s1(0)
  if (tid < H) {
    float xv0;
    if (MODE == 0) {
      xv0     = xw[((size_t)b * T_STEPS + 0) * H + i];
      xv_next = xw[((size_t)b * T_STEPS + 1) * H + i];
    } else {
      float a = 0.f;
#pragma unroll 16
      for (int k = 0; k < N_IN; ++k)
        a = fmaf(xs[0][k], win_lds[k * 257 + i], a);
      xv0 = a;
    }
    float u1 = 0.9f * m1;
    u1 = u1 + xv0;
    u1 = u1 + bin_i;
    u1 = u1 + 0.0f;          // h1 gather of zero spikes == +0.0 (np adds it too)
    u1 = u1 + bh1_i;
    bool sp = (u1 - 1.0f) > 0.0f;
    m1 = u1 - (sp ? 1.0f : 0.0f);
    unsigned long long bm = __ballot(sp);
    if ((tid & 63) == 0) s1m[0][tid >> 6] = bm;
  }
  __syncthreads();

  for (int t = 0; t < T_STEPS; ++t) {
    const int cb = t & 1;
    const int pb = cb ^ 1;

    // ---- L(t): all four walks concurrent (16 waves busy)
    if (g == 0) {
      c12v = walk16(s1m[cb], W12b, c12j, c12i, i);          // stays in register
    } else if (g == 1) {
      h2d[i] = walk16(s2m[pb], Wh2b, h2j, h2i, i);          // s2(t-1)
    } else if (g == 2) {
      h1d[i] = walk16(s1m[cb], Wh1b, h1j, h1i, i);          // for u1(t+1)
    } else {
      if (i < N_OUT) {
        if (t > WARM) {                                     // readout of s2(t-1)
          float d = walk16(s2m[pb], Wob, woj, woi, i);
          acc = acc + (d + bo_o);
        }
      } else if (MODE == 1 && i >= 64 && i < 64 + N_IN && t + 1 < T_STEPS) {
        xs[pb][i - 64] = x[(size_t)b * (T_STEPS * N_IN) + (size_t)(t + 1) * N_IN + (i - 64)];
      }
    }
    __syncthreads();

    // ---- M(t): u2(t) then u1(t+1), two ballots (tid<256)
    if (tid < H) {
      float u2 = 0.9f * m2;
      u2 = u2 + c12v;
      u2 = u2 + b12_i;
      u2 = u2 + h2d[i];
      u2 = u2 + bh2_i;
      bool sp2 = (u2 - 1.0f) > 0.0f;
      m2 = u2 - (sp2 ? 1.0f : 0.0f);
      unsigned long long bm2 = __ballot(sp2);
      if ((tid & 63) == 0) s2m[cb][tid >> 6] = bm2;

      if (t + 1 < T_STEPS) {
        float xv;
        if (MODE == 0) {
          xv = xv_next;
        } else {
          float a = 0.f;
#pragma unroll 16
          for (int k = 0; k < N_IN; ++k)
            a = fmaf(xs[pb][k], win_lds[k * 257 + i], a);
          xv = a;
        }
        float u1 = 0.9f * m1;
        u1 = u1 + xv;
        u1 = u1 + bin_i;
        u1 = u1 + h1d[i];
        u1 = u1 + bh1_i;
        bool sp1 = (u1 - 1.0f) > 0.0f;
        m1 = u1 - (sp1 ? 1.0f : 0.0f);
        unsigned long long bm1 = __ballot(sp1);
        if ((tid & 63) == 0) s1m[pb][tid >> 6] = bm1;
        if (MODE == 0 && t + 2 < T_STEPS)
          xv_next = xw[((size_t)b * T_STEPS + (t + 2)) * H + i];
      }
    }
    __syncthreads();
  }

  // ---- epilogue: readout of s2(1023) (lives in buffer (1023)&1 = 1)
  if (g == 3 && i < N_OUT) {
    float d = walk16(s2m[1], Wob, woj, woi, i);
    acc = acc + (d + bo_o);
    out[(size_t)b * N_OUT + i] = acc / 1014.0f;
  }
}

// ---------- launch ----------
extern "C" void kernel_launch(void* const* d_in, const int* in_sizes, int n_in,
                              void* d_out, int out_size, void* d_ws, size_t ws_size,
                              hipStream_t stream) {
  const float* x     = (const float*)d_in[0];
  const float* W_in  = (const float*)d_in[1];
  const float* b_in  = (const float*)d_in[2];
  const float* W_h1  = (const float*)d_in[3];
  const float* b_h1  = (const float*)d_in[4];
  const float* W_12  = (const float*)d_in[5];
  const float* b_12  = (const float*)d_in[6];
  const float* W_h2  = (const float*)d_in[7];
  const float* b_h2  = (const float*)d_in[8];
  const float* W_out = (const float*)d_in[9];
  const float* b_out = (const float*)d_in[10];
  float* out = (float*)d_out;
  float* wsf = (float*)d_ws;

  const size_t XW_FLOATS = (size_t)256 * T_STEPS * H;          // 67,108,864
  const size_t TR_FLOATS = (size_t)3 * H * H + H * N_OUT;      // 212,992
  const size_t need0 = (XW_FLOATS + TR_FLOATS) * sizeof(float);
  const size_t need1 = TR_FLOATS * sizeof(float);

  if (ws_size >= need0) {
    float* xwp = wsf;
    float* tr  = wsf + XW_FLOATS;
    srnn_xw<<<8192, 256, 0, stream>>>(x, W_in, xwp);
    srnn_prep<<<(int)(TR_FLOATS / 256), 256, 0, stream>>>(W_h1, W_12, W_h2, W_out, tr);
    srnn_scan3<0><<<256, 1024, 0, stream>>>(
        x, xwp, W_in, b_in, b_h1, b_12, b_h2,
        tr,                       H, 1,        // Wh1T[j][i]
        tr + (size_t)H * H,       H, 1,        // W12T
        tr + (size_t)2 * H * H,   H, 1,        // Wh2T
        tr + (size_t)3 * H * H,   N_OUT, 1,    // WoutT[j][o]
        b_out, out);
  } else if (ws_size >= need1) {
    float* tr = wsf;
    srnn_prep<<<(int)(TR_FLOATS / 256), 256, 0, stream>>>(W_h1, W_12, W_h2, W_out, tr);
    srnn_scan3<1><<<256, 1024, 0, stream>>>(
        x, nullptr, W_in, b_in, b_h1, b_12, b_h2,
        tr,                       H, 1,
        tr + (size_t)H * H,       H, 1,
        tr + (size_t)2 * H * H,   H, 1,
        tr + (size_t)3 * H * H,   N_OUT, 1,
        b_out, out);
  } else {
    srnn_scan3<1><<<256, 1024, 0, stream>>>(
        x, nullptr, W_in, b_in, b_h1, b_12, b_h2,
        W_h1,  1, H,                 // original layouts (strided walks)
        W_12,  1, H,
        W_h2,  1, H,
        W_out, 1, H,
        b_out, out);
  }
}